// Round 3
// baseline (2385.871 us; speedup 1.0000x reference)
//
#include <hip/hip_runtime.h>
#include <hip/hip_bf16.h>
#include <math.h>

#define NNODES 50000
#define NEDGES 800000
#define HD     256   // HEADS*DHEAD

typedef __hip_bfloat16 bf16;

__device__ __forceinline__ float b2f(bf16 v) { return __bfloat162float(v); }
__device__ __forceinline__ float ldf(const float* p) { return *p; }
__device__ __forceinline__ float ldf(const bf16* p)  { return __bfloat162float(*p); }

// ---------------- CSR build ----------------
__global__ void hist_kernel(const int* __restrict__ dst, int* __restrict__ deg, int E) {
    int e = blockIdx.x * 256 + threadIdx.x;
    if (e < E) atomicAdd(&deg[dst[e]], 1);
}

__global__ void scan_kernel(const int* __restrict__ deg, int* __restrict__ rowptr,
                            int* __restrict__ cursor, int n) {
    __shared__ int sh[1024];
    int running = 0;
    for (int base = 0; base < n; base += 1024) {
        int i = base + threadIdx.x;
        int d = (i < n) ? deg[i] : 0;
        sh[threadIdx.x] = d;
        __syncthreads();
        for (int off = 1; off < 1024; off <<= 1) {
            int t = (threadIdx.x >= (unsigned)off) ? sh[threadIdx.x - off] : 0;
            __syncthreads();
            sh[threadIdx.x] += t;
            __syncthreads();
        }
        int incl = sh[threadIdx.x];
        int tot  = sh[1023];
        __syncthreads();   // settle before next chunk overwrites sh
        if (i < n) {
            int ex = running + incl - d;
            rowptr[i] = ex;
            cursor[i] = ex;
        }
        running += tot;
    }
    if (threadIdx.x == 0) rowptr[n] = running;
}

__global__ void scatter_kernel(const int* __restrict__ dst, int* __restrict__ cursor,
                               int* __restrict__ csr, int E) {
    int e = blockIdx.x * 256 + threadIdx.x;
    if (e < E) {
        int p = atomicAdd(&cursor[dst[e]], 1);
        csr[p] = e;
    }
}

// ------- tiled GEMM: out[M x ldw](bf16) = A[M x K] @ W[K x ldw](fp32) + bias(fp32), fp32 accumulate -------
template<typename TA>
__global__ void __launch_bounds__(256) gemm_kernel(
    const TA* __restrict__ A, int lda,
    const float* __restrict__ W, int ldw,
    const float* __restrict__ bias,
    int M, int K,
    bf16* __restrict__ out)
{
    __shared__ float As[32][68];  // [k][m]
    __shared__ float Bs[32][68];  // [k][n]
    int m0 = blockIdx.x * 64, n0 = blockIdx.y * 64;
    int tid = threadIdx.x;
    int tx = tid & 15, ty = tid >> 4;
    float acc[4][4] = {};
    for (int k0 = 0; k0 < K; k0 += 32) {
        #pragma unroll
        for (int r = 0; r < 8; r++) {
            int idx = tid + r * 256;          // 2048 = 64 x 32
            int m = idx >> 5, kk = idx & 31;
            float va = 0.f;
            if (m0 + m < M) va = ldf(&A[(size_t)(m0 + m) * lda + k0 + kk]);
            As[kk][m] = va;
        }
        #pragma unroll
        for (int r = 0; r < 8; r++) {
            int idx = tid + r * 256;          // 2048 = 32 x 64
            int kk = idx >> 6, nn = idx & 63;
            Bs[kk][nn] = W[(size_t)(k0 + kk) * ldw + n0 + nn];
        }
        __syncthreads();
        #pragma unroll
        for (int kk = 0; kk < 32; kk++) {
            float a[4], b[4];
            #pragma unroll
            for (int i = 0; i < 4; i++) a[i] = As[kk][ty * 4 + i];
            #pragma unroll
            for (int j = 0; j < 4; j++) b[j] = Bs[kk][tx * 4 + j];
            #pragma unroll
            for (int i = 0; i < 4; i++)
                #pragma unroll
                for (int j = 0; j < 4; j++) acc[i][j] += a[i] * b[j];
        }
        __syncthreads();
    }
    #pragma unroll
    for (int i = 0; i < 4; i++) {
        int m = m0 + ty * 4 + i;
        if (m >= M) continue;
        #pragma unroll
        for (int j = 0; j < 4; j++) {
            int c = n0 + tx * 4 + j;
            out[(size_t)m * ldw + c] = __float2bfloat16(acc[i][j] + bias[c]);
        }
    }
}

// ---------------- fused per-node pass ----------------
// block = 1 node (4 waves, wave h = head h, lane = channel d). Recomputes q, qWe,
// skip from the shared input row (weights L2-resident); CSR edge loop gathers
// bf16 k/v; epilogue: head-mean + (sum alpha*ea)@We + skip + LayerNorm + exact GELU.
template<int FIN, typename TH>
__global__ void __launch_bounds__(256) node_pass(
    const int* __restrict__ rowptr, const int* __restrict__ csr,
    const int* __restrict__ srcArr, const float* __restrict__ eattr,
    const TH* __restrict__ hin,
    const float* __restrict__ Wq, const float* __restrict__ bq,
    const float* __restrict__ Ws, const float* __restrict__ bs,
    const bf16* __restrict__ kb, const bf16* __restrict__ vb,
    const float* __restrict__ We,
    const float* __restrict__ lng, const float* __restrict__ lnb,
    bf16* __restrict__ outB, float* __restrict__ outF)
{
    int n = blockIdx.x;
    int h = threadIdx.x >> 6, lane = threadIdx.x & 63;

    __shared__ float sh_h[FIN];
    __shared__ float sh_q[4][64];
    __shared__ float sv[4][64];
    __shared__ float se[4][16];

    for (int c = threadIdx.x; c < FIN; c += 256) sh_h[c] = ldf(&hin[(size_t)n * FIN + c]);
    __syncthreads();

    // q[h][lane]
    float qh = bq[h * 64 + lane];
    #pragma unroll 8
    for (int c = 0; c < FIN; c++) qh += sh_h[c] * Wq[(size_t)c * HD + h * 64 + lane];
    sh_q[h][lane] = qh;
    __syncthreads();

    // qWe[h][j] = sum_d q[h][d] * We[j, h*64+d]   (lanes 0..15)
    float qwe_l = 0.f;
    if (lane < 16) {
        float s = 0.f;
        #pragma unroll 8
        for (int d = 0; d < 64; d++) s += sh_q[h][d] * We[lane * HD + h * 64 + d];
        qwe_l = s;
    }

    int e0 = rowptr[n], e1 = rowptr[n + 1];
    float accv = 0.f, acce = 0.f, ssum = 0.f;
    for (int i = e0; i < e1; i++) {
        int eid = csr[i];
        int sn = srcArr[eid];
        float kv = b2f(kb[(size_t)sn * HD + h * 64 + lane]);
        float vv = b2f(vb[(size_t)sn * HD + h * 64 + lane]);
        float eav = (lane < 16) ? eattr[(size_t)eid * 16 + lane] : 0.f;
        float t = qh * kv + eav * qwe_l;
        #pragma unroll
        for (int off = 1; off < 64; off <<= 1) t += __shfl_xor(t, off);
        float a = __expf(t * 0.125f);    // SCALE = 1/sqrt(64)
        ssum += a;
        accv += a * vv;
        acce += a * eav;
    }
    float inv = (ssum > 0.f) ? 1.f / ssum : 0.f;
    sv[h][lane] = accv * inv;
    if (lane < 16) se[h][lane] = acce * inv;
    __syncthreads();

    if (h == 0) {
        int d = lane;
        // skip = h_in @ Ws + bs
        float skipd = bs[d];
        #pragma unroll 8
        for (int c = 0; c < FIN; c++) skipd += sh_h[c] * Ws[(size_t)c * 64 + d];
        // head mean of (agg_v + agg_ea @ We)
        float val = 0.f;
        #pragma unroll
        for (int hh = 0; hh < 4; hh++) {
            float xv = sv[hh][d];
            #pragma unroll
            for (int j = 0; j < 16; j++) xv += se[hh][j] * We[j * HD + hh * 64 + d];
            val += xv;
        }
        val = val * 0.25f + skipd;
        // LayerNorm over 64 channels
        float m = val;
        #pragma unroll
        for (int off = 1; off < 64; off <<= 1) m += __shfl_xor(m, off);
        m *= (1.f / 64.f);
        float diff = val - m;
        float vr = diff * diff;
        #pragma unroll
        for (int off = 1; off < 64; off <<= 1) vr += __shfl_xor(vr, off);
        vr *= (1.f / 64.f);
        float y = diff * rsqrtf(vr + 1e-5f) * lng[d] + lnb[d];
        float ge = 0.5f * y * (1.f + erff(y * 0.70710678118654752f));  // exact GELU
        if (outF) outF[(size_t)n * 64 + d] = ge;
        else      outB[(size_t)n * 64 + d] = __float2bfloat16(ge);
    }
}

extern "C" void kernel_launch(void* const* d_in, const int* in_sizes, int n_in,
                              void* d_out, int out_size, void* d_ws, size_t ws_size,
                              hipStream_t stream)
{
    const float* x     = (const float*)d_in[0];
    const int*   eidx  = (const int*)d_in[1];
    const float* eattr = (const float*)d_in[2];
    struct P { const float *Wq,*bq,*Wk,*bk,*Wv,*bv,*We,*Ws,*bs; };
    P p[3];
    for (int l = 0; l < 3; l++) {
        int base = 3 + l * 9;
        p[l].Wq = (const float*)d_in[base + 0]; p[l].bq = (const float*)d_in[base + 1];
        p[l].Wk = (const float*)d_in[base + 2]; p[l].bk = (const float*)d_in[base + 3];
        p[l].Wv = (const float*)d_in[base + 4]; p[l].bv = (const float*)d_in[base + 5];
        p[l].We = (const float*)d_in[base + 6];
        p[l].Ws = (const float*)d_in[base + 7]; p[l].bs = (const float*)d_in[base + 8];
    }
    const float* lng = (const float*)d_in[30];
    const float* lnb = (const float*)d_in[31];

    // Workspace layout — total ~61 MiB
    char* ws = (char*)d_ws;
    size_t off = 0;
    auto alloc = [&](size_t bytes) { void* pp = ws + off; off += (bytes + 255) & ~(size_t)255; return pp; };
    int*  rowptr = (int*) alloc((NNODES + 1) * 4);
    int*  cursor = (int*) alloc(NNODES * 4);
    int*  deg    = (int*) alloc(NNODES * 4);
    int*  csr    = (int*) alloc((size_t)NEDGES * 4);
    bf16* hbuf   = (bf16*)alloc((size_t)NNODES * 64 * 2);
    bf16* kb     = (bf16*)alloc((size_t)NNODES * HD * 2);
    bf16* vb     = (bf16*)alloc((size_t)NNODES * HD * 2);

    const int* srcArr = eidx;           // edge_index[0]
    const int* dstArr = eidx + NEDGES;  // edge_index[1]

    // CSR build (identical work every call)
    hipMemsetAsync(deg, 0, NNODES * 4, stream);
    hist_kernel<<<(NEDGES + 255) / 256, 256, 0, stream>>>(dstArr, deg, NEDGES);
    scan_kernel<<<1, 1024, 0, stream>>>(deg, rowptr, cursor, NNODES);
    scatter_kernel<<<(NEDGES + 255) / 256, 256, 0, stream>>>(dstArr, cursor, csr, NEDGES);

    dim3 gq((NNODES + 63) / 64, 4);
    // Layer 1: hin = x (fp32, FIN=128)
    gemm_kernel<float><<<gq, 256, 0, stream>>>(x, 128, p[0].Wk, HD, p[0].bk, NNODES, 128, kb);
    gemm_kernel<float><<<gq, 256, 0, stream>>>(x, 128, p[0].Wv, HD, p[0].bv, NNODES, 128, vb);
    node_pass<128, float><<<NNODES, 256, 0, stream>>>(rowptr, csr, srcArr, eattr, x,
        p[0].Wq, p[0].bq, p[0].Ws, p[0].bs, kb, vb, p[0].We, lng, lnb, hbuf, nullptr);
    // Layer 2: hin = hbuf (bf16, FIN=64)
    gemm_kernel<bf16><<<gq, 256, 0, stream>>>(hbuf, 64, p[1].Wk, HD, p[1].bk, NNODES, 64, kb);
    gemm_kernel<bf16><<<gq, 256, 0, stream>>>(hbuf, 64, p[1].Wv, HD, p[1].bv, NNODES, 64, vb);
    node_pass<64, bf16><<<NNODES, 256, 0, stream>>>(rowptr, csr, srcArr, eattr, hbuf,
        p[1].Wq, p[1].bq, p[1].Ws, p[1].bs, kb, vb, p[1].We, lng, lnb, hbuf, nullptr);
    // Layer 3: hin = hbuf (bf16, FIN=64), output fp32 -> d_out
    gemm_kernel<bf16><<<gq, 256, 0, stream>>>(hbuf, 64, p[2].Wk, HD, p[2].bk, NNODES, 64, kb);
    gemm_kernel<bf16><<<gq, 256, 0, stream>>>(hbuf, 64, p[2].Wv, HD, p[2].bv, NNODES, 64, vb);
    node_pass<64, bf16><<<NNODES, 256, 0, stream>>>(rowptr, csr, srcArr, eattr, hbuf,
        p[2].Wq, p[2].bq, p[2].Ws, p[2].bs, kb, vb, p[2].We, lng, lnb, nullptr, (float*)d_out);
}